// Round 1
// baseline (276.056 us; speedup 1.0000x reference)
//
#include <hip/hip_runtime.h>
#include <math.h>

#define B_ 32
#define T_ 1024
#define C_ 801
#define L_ 128
#define S_ 257            // 2*L+1
#define BLANK 800
#define NEGV -1e30f

// ---------------- Kernel 1: per-(b,t) log-sum-exp over C classes ----------------
__global__ __launch_bounds__(256) void lse_kernel(const float* __restrict__ logits,
                                                  float* __restrict__ lse) {
    const int row = blockIdx.x;                 // b*T + t
    const float* __restrict__ x = logits + (size_t)row * C_;
    const int tid  = threadIdx.x;
    const int lane = tid & 63;
    const int wid  = tid >> 6;

    // 801 elements, 256 threads -> up to 4 each
    float v0 = x[tid];
    float v1 = x[tid + 256];
    float v2 = x[tid + 512];
    bool  h3 = (tid + 768) < C_;
    float v3 = h3 ? x[tid + 768] : NEGV;

    float m = fmaxf(fmaxf(v0, v1), fmaxf(v2, v3));
    #pragma unroll
    for (int off = 32; off > 0; off >>= 1) m = fmaxf(m, __shfl_down(m, off));

    __shared__ float wred[4];
    __shared__ float bm;
    if (lane == 0) wred[wid] = m;
    __syncthreads();
    if (tid == 0) bm = fmaxf(fmaxf(wred[0], wred[1]), fmaxf(wred[2], wred[3]));
    __syncthreads();
    m = bm;

    float s = __expf(v0 - m) + __expf(v1 - m) + __expf(v2 - m);
    if (h3) s += __expf(v3 - m);
    #pragma unroll
    for (int off = 32; off > 0; off >>= 1) s += __shfl_down(s, off);
    __syncthreads();
    if (lane == 0) wred[wid] = s;
    __syncthreads();
    if (tid == 0) lse[row] = m + __logf(wred[0] + wred[1] + wred[2] + wred[3]);
}

// ---------------- Kernel 2: CTC forward recursion, one block per batch ----------------
__global__ __launch_bounds__(320) void ctc_alpha_kernel(const float* __restrict__ logits,
                                                        const int* __restrict__ labels,
                                                        const int* __restrict__ lens,
                                                        const float* __restrict__ lse,
                                                        float* __restrict__ loss) {
    const int b = blockIdx.x;
    const int s = threadIdx.x;                  // extended-label position
    const int ll = lens[b];

    __shared__ float albuf[2][S_ + 2];          // [s+2], [0..1] = NEG padding
    if (s < 2) { albuf[0][s] = NEGV; albuf[1][s] = NEGV; }

    int  cls = BLANK;
    bool allow2 = false;
    if (s < S_ && (s & 1)) {
        cls = labels[b * L_ + (s >> 1)];
        allow2 = (s >= 3) && (cls != labels[b * L_ + (s >> 1) - 1]);
    }
    const bool valid = (s < 2 * ll + 1);

    const float* __restrict__ xb   = logits + (size_t)b * T_ * C_;
    const float* __restrict__ lseb = lse + b * T_;

    // t = 0
    if (s < S_) {
        float e0 = xb[cls] - lseb[0];
        float a;
        if (s == 0)                 a = e0;
        else if (s == 1 && ll > 0)  a = e0;
        else                        a = NEGV;
        if (!valid) a = NEGV;
        albuf[0][2 + s] = a;
    }
    __syncthreads();

    // software prefetch one step ahead
    float e_next   = xb[(size_t)C_ + cls];      // t = 1 gather
    float lse_next = lseb[1];

    int cur = 0;
    for (int t = 1; t < T_; ++t) {
        const float e     = e_next;
        const float lse_t = lse_next;
        if (t + 1 < T_) {
            e_next   = xb[(size_t)(t + 1) * C_ + cls];
            lse_next = lseb[t + 1];
        }
        if (s < S_) {
            float a0 = albuf[cur][2 + s];
            float a1 = albuf[cur][1 + s];
            float a2 = allow2 ? albuf[cur][s] : NEGV;
            float m  = fmaxf(fmaxf(a0, a1), a2);
            float r  = m + __logf(__expf(a0 - m) + __expf(a1 - m) + __expf(a2 - m))
                       + (e - lse_t);
            if (!valid) r = NEGV;
            albuf[cur ^ 1][2 + s] = r;
        }
        __syncthreads();
        cur ^= 1;
    }

    if (s == 0) {
        float a1 = albuf[cur][2 + 2 * ll];
        float a2 = (ll > 0) ? albuf[cur][2 + 2 * ll - 1] : NEGV;
        float m  = fmaxf(a1, a2);
        loss[b]  = -(m + __logf(__expf(a1 - m) + __expf(a2 - m)));
    }
}

// ---------------- Kernel 3: mean over batch ----------------
__global__ void mean_kernel(const float* __restrict__ loss, float* __restrict__ out) {
    if (threadIdx.x == 0) {
        float s = 0.f;
        for (int i = 0; i < B_; ++i) s += loss[i];
        out[0] = s / (float)B_;
    }
}

extern "C" void kernel_launch(void* const* d_in, const int* in_sizes, int n_in,
                              void* d_out, int out_size, void* d_ws, size_t ws_size,
                              hipStream_t stream) {
    const float* logits = (const float*)d_in[0];
    const int*   labels = (const int*)d_in[1];
    const int*   lens   = (const int*)d_in[2];
    float* out = (float*)d_out;

    float* lse  = (float*)d_ws;                 // B*T floats
    float* loss = lse + (size_t)B_ * T_;        // B floats

    lse_kernel<<<B_ * T_, 256, 0, stream>>>(logits, lse);
    ctc_alpha_kernel<<<B_, 320, 0, stream>>>(logits, labels, lens, lse, loss);
    mean_kernel<<<1, 64, 0, stream>>>(loss, out);
}

// Round 2
// 242.407 us; speedup vs baseline: 1.1388x; 1.1388x over previous
//
#include <hip/hip_runtime.h>
#include <math.h>

#define B_ 32
#define T_ 1024
#define C_ 801
#define L_ 128
#define S_ 257            // 2*L+1
#define BLANK 800
#define RS 260            // padded emit row stride (floats)
#define DPF 11            // prefetch depth; 1023 = 93*11 exactly
#define NEGV -1e30f

// ================= NEW PATH =================

// Kernel A: fused log-sum-exp + staged linear-domain emissions
// emit[b][t][s] = (s valid) ? exp(logits[b][t][ext[s]] - lse[b][t]) : 0
__global__ __launch_bounds__(320) void stage_kernel(const float* __restrict__ logits,
                                                    const int* __restrict__ labels,
                                                    const int* __restrict__ lens,
                                                    float* __restrict__ emit) {
    const int t = blockIdx.x, b = blockIdx.y;
    const float* __restrict__ x = logits + ((size_t)b * T_ + t) * C_;
    __shared__ float xs[C_];
    __shared__ float wred[5];
    __shared__ float bval;
    const int tid = threadIdx.x, lane = tid & 63, wid = tid >> 6;

    float v0 = x[tid];
    float v1 = x[tid + 320];
    float v2 = (tid < 161) ? x[tid + 640] : NEGV;
    xs[tid] = v0;
    xs[tid + 320] = v1;
    if (tid < 161) xs[tid + 640] = v2;

    float m = fmaxf(v0, fmaxf(v1, v2));
    #pragma unroll
    for (int off = 32; off > 0; off >>= 1) m = fmaxf(m, __shfl_down(m, off));
    if (lane == 0) wred[wid] = m;
    __syncthreads();
    if (tid == 0)
        bval = fmaxf(fmaxf(wred[0], wred[1]), fmaxf(wred[2], fmaxf(wred[3], wred[4])));
    __syncthreads();
    const float gm = bval;

    float s = __expf(v0 - gm) + __expf(v1 - gm);
    if (tid < 161) s += __expf(v2 - gm);
    #pragma unroll
    for (int off = 32; off > 0; off >>= 1) s += __shfl_down(s, off);
    __syncthreads();               // everyone has read gm; safe to reuse bval
    if (lane == 0) wred[wid] = s;
    __syncthreads();
    if (tid == 0) bval = gm + __logf(wred[0] + wred[1] + wred[2] + wred[3] + wred[4]);
    __syncthreads();
    const float lse = bval;

    const int ll = lens[b];
    if (tid < RS) {
        float e = 0.f;
        if (tid < S_ && tid < 2 * ll + 1) {
            int cls = (tid & 1) ? labels[b * L_ + (tid >> 1)] : BLANK;
            e = __expf(xs[cls] - lse);
        }
        emit[((size_t)b * T_ + t) * RS + tid] = e;
    }
}

// Kernel B: linear-domain CTC forward, ONE WAVE per batch, register-resident.
// Lane l owns states s = 5l..5l+4. No barriers, no LDS, no transcendentals in loop.
__global__ __launch_bounds__(64) void ctc_lin_kernel(const float* __restrict__ emit,
                                                     const int* __restrict__ labels,
                                                     const int* __restrict__ lens,
                                                     float* __restrict__ loss) {
    const int b = blockIdx.x;
    const int lane = threadIdx.x;
    const int ll = lens[b];
    const float* __restrict__ eb = emit + (size_t)b * T_ * RS;
    const int base_s = 5 * lane;
    const int base_ld = (base_s <= 255) ? base_s : 255;   // clamp inactive lanes into valid row span

    // skip-transition masks (0/1 floats)
    float m2[5];
    #pragma unroll
    for (int j = 0; j < 5; ++j) {
        int s = base_s + j;
        float v = 0.f;
        if (s < S_ && (s & 1) && s >= 3) {
            int li = s >> 1;
            v = (labels[b * L_ + li] != labels[b * L_ + li - 1]) ? 1.f : 0.f;
        }
        m2[j] = v;
    }
    const float lz = (lane == 0) ? 0.f : 1.f;

    // t = 0 init (validity already folded into staged e)
    float p0, p1, p2, p3, p4;
    {
        const float* r0 = eb + base_ld;
        p0 = (base_s == 0) ? r0[0] : 0.f;
        p1 = (base_s + 1 == 1) ? r0[1] : 0.f;
        p2 = 0.f; p3 = 0.f; p4 = 0.f;
    }
    int E = 0;   // accumulated log2 scale

    // preload prefetch ring: rows 1..DPF
    float ebf[DPF][5];
    #pragma unroll
    for (int jj = 0; jj < DPF; ++jj) {
        const float* r = eb + (size_t)(1 + jj) * RS + base_ld;
        #pragma unroll
        for (int k = 0; k < 5; ++k) ebf[jj][k] = r[k];
    }

    for (int tb = 1; tb < T_; tb += DPF) {
        #pragma unroll
        for (int j = 0; j < DPF; ++j) {
            float sh4 = __shfl_up(p4, 1) * lz;   // alpha[s-1] for slot0
            float sh3 = __shfl_up(p3, 1) * lz;   // alpha[s-2] for slot0
            float n0 = fmaf(m2[0], sh3, p0 + sh4) * ebf[j][0];
            float n1 = fmaf(m2[1], sh4, p1 + p0) * ebf[j][1];
            float n2 = fmaf(m2[2], p0,  p2 + p1) * ebf[j][2];
            float n3 = fmaf(m2[3], p1,  p3 + p2) * ebf[j][3];
            float n4 = fmaf(m2[4], p2,  p4 + p3) * ebf[j][4];
            p0 = n0; p1 = n1; p2 = n2; p3 = n3; p4 = n4;
            // refill slot j with row (tb + j + DPF); buffer is padded past t=1023
            {
                const float* r = eb + (size_t)(tb + j + DPF) * RS + base_ld;
                #pragma unroll
                for (int k = 0; k < 5; ++k) ebf[j][k] = r[k];
            }
            if (j == 4 || j == DPF - 1) {
                // exact power-of-2 rescale (wave-uniform)
                float mx = fmaxf(fmaxf(fmaxf(p0, p1), fmaxf(p2, p3)), p4);
                #pragma unroll
                for (int off = 1; off < 64; off <<= 1) mx = fmaxf(mx, __shfl_xor(mx, off));
                int e2 = (int)((__float_as_uint(mx) >> 23) & 0xFF) - 126;
                float sc = __uint_as_float((unsigned)(127 - e2) << 23);
                p0 *= sc; p1 *= sc; p2 *= sc; p3 *= sc; p4 *= sc;
                E += e2;
            }
        }
    }

    // termination
    __shared__ float pf[5 * 64];
    pf[base_s + 0] = p0; pf[base_s + 1] = p1; pf[base_s + 2] = p2;
    pf[base_s + 3] = p3; pf[base_s + 4] = p4;
    __syncthreads();
    if (lane == 0) {
        float a1 = pf[2 * ll];
        float a2 = (ll > 0) ? pf[2 * ll - 1] : 0.f;
        loss[b] = -(__logf(a1 + a2) + (float)E * 0.69314718055994531f);
    }
}

__global__ void mean_kernel(const float* __restrict__ loss, float* __restrict__ out) {
    if (threadIdx.x == 0) {
        float s = 0.f;
        for (int i = 0; i < B_; ++i) s += loss[i];
        out[0] = s / (float)B_;
    }
}

// ================= FALLBACK PATH (round-1, needs only 131 KB ws) =================

__global__ __launch_bounds__(256) void lse_kernel(const float* __restrict__ logits,
                                                  float* __restrict__ lse) {
    const int row = blockIdx.x;
    const float* __restrict__ x = logits + (size_t)row * C_;
    const int tid = threadIdx.x, lane = tid & 63, wid = tid >> 6;
    float v0 = x[tid], v1 = x[tid + 256], v2 = x[tid + 512];
    bool h3 = (tid + 768) < C_;
    float v3 = h3 ? x[tid + 768] : NEGV;
    float m = fmaxf(fmaxf(v0, v1), fmaxf(v2, v3));
    #pragma unroll
    for (int off = 32; off > 0; off >>= 1) m = fmaxf(m, __shfl_down(m, off));
    __shared__ float wred[4]; __shared__ float bm;
    if (lane == 0) wred[wid] = m;
    __syncthreads();
    if (tid == 0) bm = fmaxf(fmaxf(wred[0], wred[1]), fmaxf(wred[2], wred[3]));
    __syncthreads();
    m = bm;
    float s = __expf(v0 - m) + __expf(v1 - m) + __expf(v2 - m);
    if (h3) s += __expf(v3 - m);
    #pragma unroll
    for (int off = 32; off > 0; off >>= 1) s += __shfl_down(s, off);
    __syncthreads();
    if (lane == 0) wred[wid] = s;
    __syncthreads();
    if (tid == 0) lse[row] = m + __logf(wred[0] + wred[1] + wred[2] + wred[3]);
}

__global__ __launch_bounds__(320) void ctc_alpha_kernel(const float* __restrict__ logits,
                                                        const int* __restrict__ labels,
                                                        const int* __restrict__ lens,
                                                        const float* __restrict__ lse,
                                                        float* __restrict__ loss) {
    const int b = blockIdx.x;
    const int s = threadIdx.x;
    const int ll = lens[b];
    __shared__ float albuf[2][S_ + 2];
    if (s < 2) { albuf[0][s] = NEGV; albuf[1][s] = NEGV; }
    int cls = BLANK; bool allow2 = false;
    if (s < S_ && (s & 1)) {
        cls = labels[b * L_ + (s >> 1)];
        allow2 = (s >= 3) && (cls != labels[b * L_ + (s >> 1) - 1]);
    }
    const bool valid = (s < 2 * ll + 1);
    const float* __restrict__ xb = logits + (size_t)b * T_ * C_;
    const float* __restrict__ lseb = lse + b * T_;
    if (s < S_) {
        float e0 = xb[cls] - lseb[0];
        float a = (s == 0 || (s == 1 && ll > 0)) ? e0 : NEGV;
        if (!valid) a = NEGV;
        albuf[0][2 + s] = a;
    }
    __syncthreads();
    float e_next = xb[(size_t)C_ + cls];
    float lse_next = lseb[1];
    int cur = 0;
    for (int t = 1; t < T_; ++t) {
        const float e = e_next, lse_t = lse_next;
        if (t + 1 < T_) { e_next = xb[(size_t)(t + 1) * C_ + cls]; lse_next = lseb[t + 1]; }
        if (s < S_) {
            float a0 = albuf[cur][2 + s];
            float a1 = albuf[cur][1 + s];
            float a2 = allow2 ? albuf[cur][s] : NEGV;
            float m = fmaxf(fmaxf(a0, a1), a2);
            float r = m + __logf(__expf(a0 - m) + __expf(a1 - m) + __expf(a2 - m)) + (e - lse_t);
            if (!valid) r = NEGV;
            albuf[cur ^ 1][2 + s] = r;
        }
        __syncthreads();
        cur ^= 1;
    }
    if (s == 0) {
        float a1 = albuf[cur][2 + 2 * ll];
        float a2 = (ll > 0) ? albuf[cur][2 + 2 * ll - 1] : NEGV;
        float m = fmaxf(a1, a2);
        loss[b] = -(m + __logf(__expf(a1 - m) + __expf(a2 - m)));
    }
}

// ================= launch =================

extern "C" void kernel_launch(void* const* d_in, const int* in_sizes, int n_in,
                              void* d_out, int out_size, void* d_ws, size_t ws_size,
                              hipStream_t stream) {
    const float* logits = (const float*)d_in[0];
    const int*   labels = (const int*)d_in[1];
    const int*   lens   = (const int*)d_in[2];
    float* out = (float*)d_out;

    const size_t emit_elems = (size_t)B_ * T_ * RS + 16 * RS;   // + prefetch overrun pad
    const size_t need = (emit_elems + B_) * sizeof(float);

    if (ws_size >= need) {
        float* emit = (float*)d_ws;
        float* loss = emit + emit_elems;
        dim3 grid(T_, B_);
        stage_kernel<<<grid, 320, 0, stream>>>(logits, labels, lens, emit);
        ctc_lin_kernel<<<B_, 64, 0, stream>>>(emit, labels, lens, loss);
        mean_kernel<<<1, 64, 0, stream>>>(loss, out);
    } else {
        float* lse  = (float*)d_ws;
        float* loss = lse + (size_t)B_ * T_;
        lse_kernel<<<B_ * T_, 256, 0, stream>>>(logits, lse);
        ctc_alpha_kernel<<<B_, 320, 0, stream>>>(logits, labels, lens, lse, loss);
        mean_kernel<<<1, 64, 0, stream>>>(loss, out);
    }
}

// Round 3
// 211.986 us; speedup vs baseline: 1.3022x; 1.1435x over previous
//
#include <hip/hip_runtime.h>
#include <math.h>

#define B_ 32
#define T_ 1024
#define C_ 801
#define L_ 128
#define S_ 257            // 2*L+1
#define BLANK 800
#define RS 260            // padded emit row stride (floats)
#define DPF 11            // prefetch depth; 1023 = 93*11 exactly
#define NEGV -1e30f

// -------- DPP helpers (VALU cross-lane; no LDS, ~5 cyc vs ds_permute ~120) --------
template <int CTRL>
__device__ __forceinline__ float dppf(float v) {
    return __uint_as_float((unsigned)__builtin_amdgcn_update_dpp(
        0, (int)__float_as_uint(v), CTRL, 0xf, 0xf, true));
}
// lane l gets lane l-1; lane 0 gets 0.0f (bound_ctrl)  [wave_shr:1 = 0x138]
__device__ __forceinline__ float shift_up1(float v) { return dppf<0x138>(v); }

// full-wave max of non-negative values, broadcast via readlane(63)
__device__ __forceinline__ float wave_max_nn(float v) {
    v = fmaxf(v, dppf<0xB1>(v));    // quad_perm [1,0,3,2]  (xor 1)
    v = fmaxf(v, dppf<0x4E>(v));    // quad_perm [2,3,0,1]  (xor 2)
    v = fmaxf(v, dppf<0x141>(v));   // row_half_mirror      (xor 4)
    v = fmaxf(v, dppf<0x140>(v));   // row_mirror           (xor 8)
    v = fmaxf(v, dppf<0x142>(v));   // row_bcast15
    v = fmaxf(v, dppf<0x143>(v));   // row_bcast31
    return __uint_as_float((unsigned)__builtin_amdgcn_readlane((int)__float_as_uint(v), 63));
}

// ================= NEW PATH =================

// Kernel A: fused log-sum-exp + staged linear-domain emissions
__global__ __launch_bounds__(320) void stage_kernel(const float* __restrict__ logits,
                                                    const int* __restrict__ labels,
                                                    const int* __restrict__ lens,
                                                    float* __restrict__ emit) {
    const int t = blockIdx.x, b = blockIdx.y;
    const float* __restrict__ x = logits + ((size_t)b * T_ + t) * C_;
    __shared__ float xs[C_];
    __shared__ float wred[5];
    __shared__ float bval;
    const int tid = threadIdx.x, lane = tid & 63, wid = tid >> 6;

    float v0 = x[tid];
    float v1 = x[tid + 320];
    float v2 = (tid < 161) ? x[tid + 640] : NEGV;
    xs[tid] = v0;
    xs[tid + 320] = v1;
    if (tid < 161) xs[tid + 640] = v2;

    float m = fmaxf(v0, fmaxf(v1, v2));
    #pragma unroll
    for (int off = 32; off > 0; off >>= 1) m = fmaxf(m, __shfl_down(m, off));
    if (lane == 0) wred[wid] = m;
    __syncthreads();
    if (tid == 0)
        bval = fmaxf(fmaxf(wred[0], wred[1]), fmaxf(wred[2], fmaxf(wred[3], wred[4])));
    __syncthreads();
    const float gm = bval;

    float s = __expf(v0 - gm) + __expf(v1 - gm);
    if (tid < 161) s += __expf(v2 - gm);
    #pragma unroll
    for (int off = 32; off > 0; off >>= 1) s += __shfl_down(s, off);
    __syncthreads();
    if (lane == 0) wred[wid] = s;
    __syncthreads();
    if (tid == 0) bval = gm + __logf(wred[0] + wred[1] + wred[2] + wred[3] + wred[4]);
    __syncthreads();
    const float lse = bval;

    const int ll = lens[b];
    if (tid < RS) {
        float e = 0.f;
        if (tid < S_ && tid < 2 * ll + 1) {
            int cls = (tid & 1) ? labels[b * L_ + (tid >> 1)] : BLANK;
            e = __expf(xs[cls] - lse);
        }
        emit[((size_t)b * T_ + t) * RS + tid] = e;
    }
}

// Kernel B: linear-domain CTC forward, one wave per batch, all-register, DPP cross-lane.
__global__ __launch_bounds__(64) void ctc_lin_kernel(const float* __restrict__ emit,
                                                     const int* __restrict__ labels,
                                                     const int* __restrict__ lens,
                                                     float* __restrict__ loss) {
    const int b = blockIdx.x;
    const int lane = threadIdx.x;
    const int ll = lens[b];
    const float* __restrict__ eb = emit + (size_t)b * T_ * RS;
    const int base_s = 5 * lane;
    const int base_ld = (base_s <= 255) ? base_s : 255;

    float m2[5];
    #pragma unroll
    for (int j = 0; j < 5; ++j) {
        int s = base_s + j;
        float v = 0.f;
        if (s < S_ && (s & 1) && s >= 3) {
            int li = s >> 1;
            v = (labels[b * L_ + li] != labels[b * L_ + li - 1]) ? 1.f : 0.f;
        }
        m2[j] = v;
    }

    float p0, p1, p2, p3, p4;
    {
        const float* r0 = eb + base_ld;
        p0 = (base_s == 0) ? r0[0] : 0.f;
        p1 = (base_s + 1 == 1) ? r0[1] : 0.f;
        p2 = 0.f; p3 = 0.f; p4 = 0.f;
    }
    int E = 0;

    float ebf[DPF][5];
    #pragma unroll
    for (int jj = 0; jj < DPF; ++jj) {
        const float* r = eb + (size_t)(1 + jj) * RS + base_ld;
        #pragma unroll
        for (int k = 0; k < 5; ++k) ebf[jj][k] = r[k];
    }

    for (int tb = 1; tb < T_; tb += DPF) {
        #pragma unroll
        for (int j = 0; j < DPF; ++j) {
            float sh4 = shift_up1(p4);   // alpha[s-1] for slot0
            float sh3 = shift_up1(p3);   // alpha[s-2] for slot0
            float n0 = fmaf(m2[0], sh3, p0 + sh4) * ebf[j][0];
            float n1 = fmaf(m2[1], sh4, p1 + p0) * ebf[j][1];
            float n2 = fmaf(m2[2], p0,  p2 + p1) * ebf[j][2];
            float n3 = fmaf(m2[3], p1,  p3 + p2) * ebf[j][3];
            float n4 = fmaf(m2[4], p2,  p4 + p3) * ebf[j][4];
            p0 = n0; p1 = n1; p2 = n2; p3 = n3; p4 = n4;
            {
                const float* r = eb + (size_t)(tb + j + DPF) * RS + base_ld;
                #pragma unroll
                for (int k = 0; k < 5; ++k) ebf[j][k] = r[k];
            }
            if (j == 4 || j == DPF - 1) {
                float mx = fmaxf(fmaxf(fmaxf(p0, p1), fmaxf(p2, p3)), p4);
                mx = wave_max_nn(mx);
                int e2 = (int)((__float_as_uint(mx) >> 23) & 0xFF) - 126;
                float sc = __uint_as_float((unsigned)(127 - e2) << 23);
                p0 *= sc; p1 *= sc; p2 *= sc; p3 *= sc; p4 *= sc;
                E += e2;
            }
        }
    }

    __shared__ float pf[5 * 64];
    pf[base_s + 0] = p0; pf[base_s + 1] = p1; pf[base_s + 2] = p2;
    pf[base_s + 3] = p3; pf[base_s + 4] = p4;
    __syncthreads();
    if (lane == 0) {
        float a1 = pf[2 * ll];
        float a2 = (ll > 0) ? pf[2 * ll - 1] : 0.f;
        loss[b] = -(__logf(a1 + a2) + (float)E * 0.69314718055994531f);
    }
}

__global__ void mean_kernel(const float* __restrict__ loss, float* __restrict__ out) {
    if (threadIdx.x == 0) {
        float s = 0.f;
        for (int i = 0; i < B_; ++i) s += loss[i];
        out[0] = s / (float)B_;
    }
}

// ================= FALLBACK PATH (small ws) =================

__global__ __launch_bounds__(256) void lse_kernel(const float* __restrict__ logits,
                                                  float* __restrict__ lse) {
    const int row = blockIdx.x;
    const float* __restrict__ x = logits + (size_t)row * C_;
    const int tid = threadIdx.x, lane = tid & 63, wid = tid >> 6;
    float v0 = x[tid], v1 = x[tid + 256], v2 = x[tid + 512];
    bool h3 = (tid + 768) < C_;
    float v3 = h3 ? x[tid + 768] : NEGV;
    float m = fmaxf(fmaxf(v0, v1), fmaxf(v2, v3));
    #pragma unroll
    for (int off = 32; off > 0; off >>= 1) m = fmaxf(m, __shfl_down(m, off));
    __shared__ float wred[4]; __shared__ float bm;
    if (lane == 0) wred[wid] = m;
    __syncthreads();
    if (tid == 0) bm = fmaxf(fmaxf(wred[0], wred[1]), fmaxf(wred[2], wred[3]));
    __syncthreads();
    m = bm;
    float s = __expf(v0 - m) + __expf(v1 - m) + __expf(v2 - m);
    if (h3) s += __expf(v3 - m);
    #pragma unroll
    for (int off = 32; off > 0; off >>= 1) s += __shfl_down(s, off);
    __syncthreads();
    if (lane == 0) wred[wid] = s;
    __syncthreads();
    if (tid == 0) lse[row] = m + __logf(wred[0] + wred[1] + wred[2] + wred[3]);
}

__global__ __launch_bounds__(320) void ctc_alpha_kernel(const float* __restrict__ logits,
                                                        const int* __restrict__ labels,
                                                        const int* __restrict__ lens,
                                                        const float* __restrict__ lse,
                                                        float* __restrict__ loss) {
    const int b = blockIdx.x;
    const int s = threadIdx.x;
    const int ll = lens[b];
    __shared__ float albuf[2][S_ + 2];
    if (s < 2) { albuf[0][s] = NEGV; albuf[1][s] = NEGV; }
    int cls = BLANK; bool allow2 = false;
    if (s < S_ && (s & 1)) {
        cls = labels[b * L_ + (s >> 1)];
        allow2 = (s >= 3) && (cls != labels[b * L_ + (s >> 1) - 1]);
    }
    const bool valid = (s < 2 * ll + 1);
    const float* __restrict__ xb = logits + (size_t)b * T_ * C_;
    const float* __restrict__ lseb = lse + b * T_;
    if (s < S_) {
        float e0 = xb[cls] - lseb[0];
        float a = (s == 0 || (s == 1 && ll > 0)) ? e0 : NEGV;
        if (!valid) a = NEGV;
        albuf[0][2 + s] = a;
    }
    __syncthreads();
    float e_next = xb[(size_t)C_ + cls];
    float lse_next = lseb[1];
    int cur = 0;
    for (int t = 1; t < T_; ++t) {
        const float e = e_next, lse_t = lse_next;
        if (t + 1 < T_) { e_next = xb[(size_t)(t + 1) * C_ + cls]; lse_next = lseb[t + 1]; }
        if (s < S_) {
            float a0 = albuf[cur][2 + s];
            float a1 = albuf[cur][1 + s];
            float a2 = allow2 ? albuf[cur][s] : NEGV;
            float m = fmaxf(fmaxf(a0, a1), a2);
            float r = m + __logf(__expf(a0 - m) + __expf(a1 - m) + __expf(a2 - m)) + (e - lse_t);
            if (!valid) r = NEGV;
            albuf[cur ^ 1][2 + s] = r;
        }
        __syncthreads();
        cur ^= 1;
    }
    if (s == 0) {
        float a1 = albuf[cur][2 + 2 * ll];
        float a2 = (ll > 0) ? albuf[cur][2 + 2 * ll - 1] : NEGV;
        float m = fmaxf(a1, a2);
        loss[b] = -(m + __logf(__expf(a1 - m) + __expf(a2 - m)));
    }
}

// ================= launch =================

extern "C" void kernel_launch(void* const* d_in, const int* in_sizes, int n_in,
                              void* d_out, int out_size, void* d_ws, size_t ws_size,
                              hipStream_t stream) {
    const float* logits = (const float*)d_in[0];
    const int*   labels = (const int*)d_in[1];
    const int*   lens   = (const int*)d_in[2];
    float* out = (float*)d_out;

    const size_t emit_elems = (size_t)B_ * T_ * RS + 16 * RS;
    const size_t need = (emit_elems + B_) * sizeof(float);

    if (ws_size >= need) {
        float* emit = (float*)d_ws;
        float* loss = emit + emit_elems;
        dim3 grid(T_, B_);
        stage_kernel<<<grid, 320, 0, stream>>>(logits, labels, lens, emit);
        ctc_lin_kernel<<<B_, 64, 0, stream>>>(emit, labels, lens, loss);
        mean_kernel<<<1, 64, 0, stream>>>(loss, out);
    } else {
        float* lse  = (float*)d_ws;
        float* loss = lse + (size_t)B_ * T_;
        lse_kernel<<<B_ * T_, 256, 0, stream>>>(logits, lse);
        ctc_alpha_kernel<<<B_, 320, 0, stream>>>(logits, labels, lens, lse, loss);
        mean_kernel<<<1, 64, 0, stream>>>(loss, out);
    }
}

// Round 4
// 136.488 us; speedup vs baseline: 2.0226x; 1.5531x over previous
//
#include <hip/hip_runtime.h>
#include <math.h>

#define B_ 32
#define T_ 1024
#define C_ 801
#define L_ 128
#define S_ 257            // 2*L+1
#define BLANK 800
#define RS 260            // padded emit row stride (floats); 1040B, 16B-aligned
#define NEGV -1e30f

// -------- DPP helpers (validated R3: bit-identical to shfl path) --------
template <int CTRL>
__device__ __forceinline__ float dppf(float v) {
    return __uint_as_float((unsigned)__builtin_amdgcn_update_dpp(
        0, (int)__float_as_uint(v), CTRL, 0xf, 0xf, true));
}
// lane l gets lane l-1's value; lane 0 gets 0.0f   [wave_shr:1]
__device__ __forceinline__ float shift_up1(float v) { return dppf<0x138>(v); }

// full-wave max of non-negative values, broadcast via readlane(63)
__device__ __forceinline__ float wave_max_nn(float v) {
    v = fmaxf(v, dppf<0xB1>(v));    // quad_perm xor1
    v = fmaxf(v, dppf<0x4E>(v));    // quad_perm xor2
    v = fmaxf(v, dppf<0x141>(v));   // row_half_mirror (xor 4)
    v = fmaxf(v, dppf<0x140>(v));   // row_mirror      (xor 8)
    v = fmaxf(v, dppf<0x142>(v));   // row_bcast15
    v = fmaxf(v, dppf<0x143>(v));   // row_bcast31
    return __uint_as_float((unsigned)__builtin_amdgcn_readlane((int)__float_as_uint(v), 63));
}

// ================= Kernel A: fused LSE + staged linear-domain emissions =================
__global__ __launch_bounds__(320) void stage_kernel(const float* __restrict__ logits,
                                                    const int* __restrict__ labels,
                                                    const int* __restrict__ lens,
                                                    float* __restrict__ emit) {
    const int t = blockIdx.x, b = blockIdx.y;
    const float* __restrict__ x = logits + ((size_t)b * T_ + t) * C_;
    __shared__ float xs[C_];
    __shared__ float wred[5];
    __shared__ float bval;
    const int tid = threadIdx.x, lane = tid & 63, wid = tid >> 6;

    float v0 = x[tid];
    float v1 = x[tid + 320];
    float v2 = (tid < 161) ? x[tid + 640] : NEGV;
    xs[tid] = v0;
    xs[tid + 320] = v1;
    if (tid < 161) xs[tid + 640] = v2;

    float m = fmaxf(v0, fmaxf(v1, v2));
    #pragma unroll
    for (int off = 32; off > 0; off >>= 1) m = fmaxf(m, __shfl_down(m, off));
    if (lane == 0) wred[wid] = m;
    __syncthreads();
    if (tid == 0)
        bval = fmaxf(fmaxf(wred[0], wred[1]), fmaxf(wred[2], fmaxf(wred[3], wred[4])));
    __syncthreads();
    const float gm = bval;

    float s = __expf(v0 - gm) + __expf(v1 - gm);
    if (tid < 161) s += __expf(v2 - gm);
    #pragma unroll
    for (int off = 32; off > 0; off >>= 1) s += __shfl_down(s, off);
    __syncthreads();
    if (lane == 0) wred[wid] = s;
    __syncthreads();
    if (tid == 0) bval = gm + __logf(wred[0] + wred[1] + wred[2] + wred[3] + wred[4]);
    __syncthreads();
    const float lse = bval;

    const int ll = lens[b];
    if (tid < RS) {
        float e = 0.f;
        if (tid < S_ && tid < 2 * ll + 1) {
            int cls = (tid & 1) ? labels[b * L_ + (tid >> 1)] : BLANK;
            e = __expf(xs[cls] - lse);
        }
        emit[((size_t)b * T_ + t) * RS + tid] = e;
    }
}

// ================= Kernel B: linear CTC forward, 1 wave/batch, float4 + named pipeline =================
// Lane l owns states 4l..4l+3 (0..255); state 256 is a scalar side-chain (real on lane 63).
__global__ __launch_bounds__(64) void ctc_lin_kernel(const float* __restrict__ emit,
                                                     const int* __restrict__ labels,
                                                     const int* __restrict__ lens,
                                                     float* __restrict__ loss) {
    const int b = blockIdx.x;
    const int lane = threadIdx.x;
    const int ll = lens[b];
    const float* __restrict__ eb = emit + (size_t)b * T_ * RS;

    // skip masks: only odd states (j=1,3) are labels
    float m21 = 0.f, m23 = 0.f;
    {
        int s1 = 4 * lane + 1;
        if (s1 >= 3) {
            int li = s1 >> 1;   // 2*lane
            m21 = (labels[b * L_ + li] != labels[b * L_ + li - 1]) ? 1.f : 0.f;
        }
        int li3 = (4 * lane + 3) >> 1;  // 2*lane+1
        m23 = (labels[b * L_ + li3] != labels[b * L_ + li3 - 1]) ? 1.f : 0.f;
    }

    // t = 0 init (emit already folds validity)
    float p0, p1, p2, p3, q;
    {
        float4 e0v = *(const float4*)(eb + 4 * lane);
        p0 = (lane == 0) ? e0v.x : 0.f;
        p1 = (lane == 0) ? e0v.y : 0.f;
        p2 = 0.f; p3 = 0.f; q = 0.f;
    }
    int E = 0;

    // named prefetch stages, depth 11 (1023 = 93*11)
#define DECL_STAGE(i) float4 ea##i; float eq##i;
    DECL_STAGE(0) DECL_STAGE(1) DECL_STAGE(2) DECL_STAGE(3) DECL_STAGE(4)
    DECL_STAGE(5) DECL_STAGE(6) DECL_STAGE(7) DECL_STAGE(8) DECL_STAGE(9) DECL_STAGE(10)

#define LOAD_STAGE(i, trow) { const float* r_ = eb + (size_t)(trow) * RS;        \
        ea##i = *(const float4*)(r_ + 4 * lane);  eq##i = r_[256]; }

#define STEP(i) {                                                                \
        float shp3 = shift_up1(p3);                                              \
        float n0 = (p0 + shp3) * ea##i.x;                                        \
        float n1 = fmaf(m21, shp3, p1 + p0) * ea##i.y;                           \
        float n2 = (p2 + p1) * ea##i.z;                                          \
        float n3 = fmaf(m23, p1, p3 + p2) * ea##i.w;                             \
        q = (q + p3) * eq##i;                                                    \
        p0 = n0; p1 = n1; p2 = n2; p3 = n3; }

#define RESCALE {                                                                \
        float mx = fmaxf(fmaxf(p0, p1), fmaxf(p2, fmaxf(p3, q)));                \
        mx = wave_max_nn(mx);                                                    \
        int e2_ = (int)((__float_as_uint(mx) >> 23) & 0xFF) - 126;               \
        float sc_ = __uint_as_float((unsigned)(127 - e2_) << 23);                \
        p0 *= sc_; p1 *= sc_; p2 *= sc_; p3 *= sc_; q *= sc_;                    \
        E += e2_; }

    LOAD_STAGE(0, 1)  LOAD_STAGE(1, 2)  LOAD_STAGE(2, 3)  LOAD_STAGE(3, 4)
    LOAD_STAGE(4, 5)  LOAD_STAGE(5, 6)  LOAD_STAGE(6, 7)  LOAD_STAGE(7, 8)
    LOAD_STAGE(8, 9)  LOAD_STAGE(9, 10) LOAD_STAGE(10, 11)

    for (int tb = 1; tb < T_; tb += 11) {
        STEP(0)  LOAD_STAGE(0, tb + 11)
        STEP(1)  LOAD_STAGE(1, tb + 12)
        STEP(2)  LOAD_STAGE(2, tb + 13)
        STEP(3)  LOAD_STAGE(3, tb + 14)
        STEP(4)  LOAD_STAGE(4, tb + 15)  RESCALE
        STEP(5)  LOAD_STAGE(5, tb + 16)
        STEP(6)  LOAD_STAGE(6, tb + 17)
        STEP(7)  LOAD_STAGE(7, tb + 18)
        STEP(8)  LOAD_STAGE(8, tb + 19)
        STEP(9)  LOAD_STAGE(9, tb + 20)
        STEP(10) LOAD_STAGE(10, tb + 21) RESCALE
    }
#undef STEP
#undef LOAD_STAGE
#undef DECL_STAGE
#undef RESCALE

    __shared__ float pf[S_];
    *(float4*)(pf + 4 * lane) = make_float4(p0, p1, p2, p3);
    if (lane == 63) pf[256] = q;
    __syncthreads();
    if (lane == 0) {
        float a1 = pf[2 * ll];
        float a2 = (ll > 0) ? pf[2 * ll - 1] : 0.f;
        loss[b] = -(__logf(a1 + a2) + (float)E * 0.69314718055994531f);
    }
}

__global__ void mean_kernel(const float* __restrict__ loss, float* __restrict__ out) {
    if (threadIdx.x == 0) {
        float s = 0.f;
        for (int i = 0; i < B_; ++i) s += loss[i];
        out[0] = s / (float)B_;
    }
}

// ================= FALLBACK PATH (small ws) =================

__global__ __launch_bounds__(256) void lse_kernel(const float* __restrict__ logits,
                                                  float* __restrict__ lse) {
    const int row = blockIdx.x;
    const float* __restrict__ x = logits + (size_t)row * C_;
    const int tid = threadIdx.x, lane = tid & 63, wid = tid >> 6;
    float v0 = x[tid], v1 = x[tid + 256], v2 = x[tid + 512];
    bool h3 = (tid + 768) < C_;
    float v3 = h3 ? x[tid + 768] : NEGV;
    float m = fmaxf(fmaxf(v0, v1), fmaxf(v2, v3));
    #pragma unroll
    for (int off = 32; off > 0; off >>= 1) m = fmaxf(m, __shfl_down(m, off));
    __shared__ float wred[4]; __shared__ float bm;
    if (lane == 0) wred[wid] = m;
    __syncthreads();
    if (tid == 0) bm = fmaxf(fmaxf(wred[0], wred[1]), fmaxf(wred[2], wred[3]));
    __syncthreads();
    m = bm;
    float s = __expf(v0 - m) + __expf(v1 - m) + __expf(v2 - m);
    if (h3) s += __expf(v3 - m);
    #pragma unroll
    for (int off = 32; off > 0; off >>= 1) s += __shfl_down(s, off);
    __syncthreads();
    if (lane == 0) wred[wid] = s;
    __syncthreads();
    if (tid == 0) lse[row] = m + __logf(wred[0] + wred[1] + wred[2] + wred[3]);
}

__global__ __launch_bounds__(320) void ctc_alpha_kernel(const float* __restrict__ logits,
                                                        const int* __restrict__ labels,
                                                        const int* __restrict__ lens,
                                                        const float* __restrict__ lse,
                                                        float* __restrict__ loss) {
    const int b = blockIdx.x;
    const int s = threadIdx.x;
    const int ll = lens[b];
    __shared__ float albuf[2][S_ + 2];
    if (s < 2) { albuf[0][s] = NEGV; albuf[1][s] = NEGV; }
    int cls = BLANK; bool allow2 = false;
    if (s < S_ && (s & 1)) {
        cls = labels[b * L_ + (s >> 1)];
        allow2 = (s >= 3) && (cls != labels[b * L_ + (s >> 1) - 1]);
    }
    const bool valid = (s < 2 * ll + 1);
    const float* __restrict__ xb = logits + (size_t)b * T_ * C_;
    const float* __restrict__ lseb = lse + b * T_;
    if (s < S_) {
        float e0 = xb[cls] - lseb[0];
        float a = (s == 0 || (s == 1 && ll > 0)) ? e0 : NEGV;
        if (!valid) a = NEGV;
        albuf[0][2 + s] = a;
    }
    __syncthreads();
    float e_next = xb[(size_t)C_ + cls];
    float lse_next = lseb[1];
    int cur = 0;
    for (int t = 1; t < T_; ++t) {
        const float e = e_next, lse_t = lse_next;
        if (t + 1 < T_) { e_next = xb[(size_t)(t + 1) * C_ + cls]; lse_next = lseb[t + 1]; }
        if (s < S_) {
            float a0 = albuf[cur][2 + s];
            float a1 = albuf[cur][1 + s];
            float a2 = allow2 ? albuf[cur][s] : NEGV;
            float m = fmaxf(fmaxf(a0, a1), a2);
            float r = m + __logf(__expf(a0 - m) + __expf(a1 - m) + __expf(a2 - m)) + (e - lse_t);
            if (!valid) r = NEGV;
            albuf[cur ^ 1][2 + s] = r;
        }
        __syncthreads();
        cur ^= 1;
    }
    if (s == 0) {
        float a1 = albuf[cur][2 + 2 * ll];
        float a2 = (ll > 0) ? albuf[cur][2 + 2 * ll - 1] : NEGV;
        float m = fmaxf(a1, a2);
        loss[b] = -(m + __logf(__expf(a1 - m) + __expf(a2 - m)));
    }
}

// ================= launch =================

extern "C" void kernel_launch(void* const* d_in, const int* in_sizes, int n_in,
                              void* d_out, int out_size, void* d_ws, size_t ws_size,
                              hipStream_t stream) {
    const float* logits = (const float*)d_in[0];
    const int*   labels = (const int*)d_in[1];
    const int*   lens   = (const int*)d_in[2];
    float* out = (float*)d_out;

    const size_t emit_elems = (size_t)B_ * T_ * RS + 32 * RS;   // pad > pipeline overrun
    const size_t need = (emit_elems + B_) * sizeof(float);

    if (ws_size >= need) {
        float* emit = (float*)d_ws;
        float* loss = emit + emit_elems;
        dim3 grid(T_, B_);
        stage_kernel<<<grid, 320, 0, stream>>>(logits, labels, lens, emit);
        ctc_lin_kernel<<<B_, 64, 0, stream>>>(emit, labels, lens, loss);
        mean_kernel<<<1, 64, 0, stream>>>(loss, out);
    } else {
        float* lse  = (float*)d_ws;
        float* loss = lse + (size_t)B_ * T_;
        lse_kernel<<<B_ * T_, 256, 0, stream>>>(logits, lse);
        ctc_alpha_kernel<<<B_, 320, 0, stream>>>(logits, labels, lens, lse, loss);
        mean_kernel<<<1, 64, 0, stream>>>(loss, out);
    }
}